// Round 9
// baseline (762.972 us; speedup 1.0000x reference)
//
#include <hip/hip_runtime.h>
#include <stdint.h>

// Problem constants: z (8,64,16,32,32) f32, codebook (512,64), N = 8*16*32*32
#define N_ 131072
#define K_ 512

// out offsets (in floats): z_q_st, z_q, indices, cb, cs, ea
#define OFF_ZQ   8388608
#define OFF_IDX  16777216
#define OFF_CB   16908288
#define OFF_CS   16941056
#define OFF_EA   16941568

// ws offsets (bytes)
#define WS_IDX   0         // int32 x 131072
#define WS_CNT   524288    // f32 x 512   (final counts)
#define WS_ESUM  526336    // f32 x 32768 (final embed_sum)
#define WS_CNORM 657408    // f32 x 512
#define WS_RIDX  659456    // int32 x 512
#define WS_NOISE 661504    // f32 x 32768
#define WS_PART  792576    // NB x (128KB esum partial) then NB x (2KB count partial)

// ---- JAX threefry2x32 (20 rounds), bit-exact ----
__device__ __forceinline__ void threefry(uint32_t k0, uint32_t k1,
                                         uint32_t x0, uint32_t x1,
                                         uint32_t& y0, uint32_t& y1) {
  uint32_t ks[3] = {k0, k1, k0 ^ k1 ^ 0x1BD11BDAu};
  const int R0[4] = {13, 15, 26, 6};
  const int R1[4] = {17, 29, 16, 24};
  x0 += ks[0]; x1 += ks[1];
  #pragma unroll
  for (int i = 0; i < 5; i++) {
    #pragma unroll
    for (int j = 0; j < 4; j++) {
      int r = (i & 1) ? R1[j] : R0[j];
      x0 += x1;
      x1 = (x1 << r) | (x1 >> (32 - r));
      x1 ^= x0;
    }
    x0 += ks[(i + 1) % 3];
    x1 += ks[(i + 2) % 3] + (uint32_t)(i + 1);
  }
  y0 = x0; y1 = x1;
}

// Giles erfinv (same polynomial XLA uses for f32)
__device__ __forceinline__ float erfinv_f(float x) {
  float w = -log1pf(-x * x);
  float p;
  if (w < 5.0f) {
    w -= 2.5f;
    p = 2.81022636e-08f;
    p = fmaf(p, w, 3.43273939e-07f);
    p = fmaf(p, w, -3.5233877e-06f);
    p = fmaf(p, w, -4.39150654e-06f);
    p = fmaf(p, w, 0.00021858087f);
    p = fmaf(p, w, -0.00125372503f);
    p = fmaf(p, w, -0.00417768164f);
    p = fmaf(p, w, 0.246640727f);
    p = fmaf(p, w, 1.50140941f);
  } else {
    w = sqrtf(w) - 3.0f;
    p = -0.000200214257f;
    p = fmaf(p, w, 0.000100950558f);
    p = fmaf(p, w, 0.00134934322f);
    p = fmaf(p, w, -0.00367342844f);
    p = fmaf(p, w, 0.00573950773f);
    p = fmaf(p, w, -0.0076224613f);
    p = fmaf(p, w, 0.00943887047f);
    p = fmaf(p, w, 1.00167406f);
    p = fmaf(p, w, 2.83297682f);
  }
  return p * x;
}

// RNG (ridx exact, noise approx-exact) + codebook row norms
__global__ __launch_bounds__(256) void k_rng(const float* __restrict__ cb,
                                             float* __restrict__ noise,
                                             int* __restrict__ ridx,
                                             float* __restrict__ cnorm) {
  int t = blockIdx.x * 256 + threadIdx.x;
  if (t < 16384) {
    // normal(key(2), (32768,)): pairs (i, i+16384)
    uint32_t y0, y1;
    threefry(0u, 2u, (uint32_t)t, (uint32_t)(t + 16384), y0, y1);
    const float lo = -0.99999994f;  // nextafter(-1, 0)
    float f0 = __uint_as_float(0x3F800000u | (y0 >> 9)) - 1.0f;
    float f1 = __uint_as_float(0x3F800000u | (y1 >> 9)) - 1.0f;
    float u0 = fmaxf(lo, f0 * 2.0f + lo);
    float u1 = fmaxf(lo, f1 * 2.0f + lo);
    noise[t]         = 1.41421356237309515f * erfinv_f(u0);
    noise[t + 16384] = 1.41421356237309515f * erfinv_f(u1);
  } else if (t < 16640) {
    // randint(key(1), (512,), 0, 131072): span=2^17 divides 2^32 so result
    // = lower_bits % 2^17, lower_bits from k2 of split(key(1)).
    int i = t - 16384;
    uint32_t a0, b0, a1, b1;
    threefry(0u, 1u, 0u, 2u, a0, b0);  // split lane 0
    threefry(0u, 1u, 1u, 3u, a1, b1);  // split lane 1 ; k2 = (b0, b1)
    uint32_t y0, y1;
    threefry(b0, b1, (uint32_t)i, (uint32_t)(i + 256), y0, y1);
    ridx[i]       = (int)(y0 & 0x1FFFFu);
    ridx[i + 256] = (int)(y1 & 0x1FFFFu);
  } else if (t < 17152) {
    int k = t - 16640;
    const float* ck = cb + (k << 6);
    float s = 0.f;
    #pragma unroll
    for (int c = 0; c < 64; c++) s = fmaf(ck[c], ck[c], s);
    cnorm[k] = s;
  }
}

// Fused distances + argmin + z_q/z_q_st stores. 4-wave K-split:
// block = 64 points; wave w scans codes [128w, 128w+128) with the SAME
// per-k serial fmaf chain as the validated full scan (bit-identical d),
// then an order-preserving LDS combine (ascending chunk, strict <) which
// reproduces global first-min argmin exactly. 2 codes/iter = 2 independent
// FMA chains for ILP; k-loop unroll capped to keep SGPR prefetch depth sane.
__global__ __launch_bounds__(256, 4) void k_argmin_zq(const float* __restrict__ z,
                                                      const float* __restrict__ cb,
                                                      const float* __restrict__ cnorm,
                                                      int* __restrict__ idxi,
                                                      float* __restrict__ out) {
  __shared__ float ld[256];
  __shared__ int   li[256];
  int tid = threadIdx.x;
  int wave = tid >> 6, lane = tid & 63;
  int n = blockIdx.x * 64 + lane;          // point index (lane-consecutive s)
  int b = n >> 14, s = n & 16383;
  const float* zp = z + ((size_t)b << 20) + s;
  float zv[64];
  #pragma unroll
  for (int c = 0; c < 64; c++) zv[c] = zp[(size_t)c << 14];  // coalesced per c
  float z2 = 0.f;
  #pragma unroll
  for (int c = 0; c < 64; c++) z2 = fmaf(zv[c], zv[c], z2);
  int k0 = wave << 7;
  float best = 3.4028235e38f; int bi = k0;
  #pragma unroll 1
  for (int k = k0; k < k0 + 128; k += 2) {
    const float* ca = cb + (k << 6);       // wave-uniform -> scalar loads
    const float* cbp = ca + 64;
    float da = 0.f, db = 0.f;
    #pragma unroll
    for (int c = 0; c < 64; c++) {
      da = fmaf(zv[c], ca[c], da);         // same chain order as validated scan
      db = fmaf(zv[c], cbp[c], db);
    }
    float d1 = (z2 + cnorm[k])     - 2.0f * da;
    float d2 = (z2 + cnorm[k + 1]) - 2.0f * db;
    if (d1 < best) { best = d1; bi = k; }      // first-min tie-break
    if (d2 < best) { best = d2; bi = k + 1; }
  }
  ld[tid] = best; li[tid] = bi;
  __syncthreads();
  float fb = ld[lane]; int fi = li[lane];
  #pragma unroll
  for (int w = 1; w < 4; w++) {
    float d = ld[(w << 6) + lane];
    int   i2 = li[(w << 6) + lane];
    if (d < fb) { fb = d; fi = i2; }       // strict < keeps lowest chunk on ties
  }
  if (wave == 0) {
    idxi[n] = fi;
    out[OFF_IDX + n] = (float)fi;
  }
  const float* cq = cb + (fi << 6);        // per-lane gather, cb L2-resident
  float* o1 = out + ((size_t)b << 20) + s; // z_q_st
  float* o2 = o1 + OFF_ZQ;                 // z_q
  #pragma unroll
  for (int cc = 0; cc < 16; cc++) {        // stores split: wave w owns 16 c's
    int c = (wave << 4) + cc;
    float q = cq[c];
    float zc = zv[c];
    o1[(size_t)c << 14] = zc + (q - zc);   // fp-exact as reference computes it
    o2[(size_t)c << 14] = q;
  }
}

// LDS histogram of embed_sum[K][C] + counts[K]; zero global atomics on the
// main path (partials flushed with plain coalesced stores, reduced by k_hred).
// XOR bank swizzle (c ^ (k&31)): lanes-over-s accumulation would otherwise put
// all 64 lanes in bank c%32.
__global__ __launch_bounds__(256) void k_hist(const float* __restrict__ z,
                                              const int* __restrict__ idxi,
                                              float* __restrict__ pesum,
                                              float* __restrict__ pcnt,
                                              int ppb, int atomicFlush) {
  __shared__ float hist[32768];   // 128 KB
  __shared__ float cnt[512];
  int tid = threadIdx.x;
  for (int i = tid; i < 32768; i += 256) hist[i] = 0.f;
  if (tid < 256) { cnt[tid] = 0.f; cnt[tid + 256] = 0.f; }
  __syncthreads();
  int wave = tid >> 6, lane = tid & 63;
  int base = blockIdx.x * ppb;
  for (int g0 = wave * 64; g0 < ppb; g0 += 256) {
    int n = base + g0 + lane;
    int b = n >> 14, s = n & 16383;
    int k = idxi[n];
    const float* zp = z + ((size_t)b << 20) + s;
    atomicAdd(&cnt[k], 1.0f);
    int hb = k << 6, sw = k & 31;
    #pragma unroll 8
    for (int c = 0; c < 64; c++)
      atomicAdd(&hist[hb + (c ^ sw)], zp[(size_t)c << 14]);  // coalesced z read
  }
  __syncthreads();
  size_t pb = (size_t)blockIdx.x * 32768;
  for (int i = tid; i < 32768; i += 256) {
    int k = i >> 6, c = i & 63;
    float v = hist[(k << 6) + (c ^ (k & 31))];  // un-swizzle; LDS read conflict-free
    if (atomicFlush) { if (v != 0.f) atomicAdd(&pesum[i], v); }
    else pesum[pb + i] = v;
  }
  if (tid < 256) {
    #pragma unroll
    for (int j = 0; j < 2; j++) {
      int i = tid + j * 256;
      float v = cnt[i];
      if (atomicFlush) { if (v != 0.f) atomicAdd(&pcnt[i], v); }
      else pcnt[blockIdx.x * 512 + i] = v;
    }
  }
}

// Reduce NB partials -> final esum[32768] + counts[512]
__global__ __launch_bounds__(256) void k_hred(const float* __restrict__ pesum,
                                              const float* __restrict__ pcnt,
                                              float* __restrict__ esum,
                                              float* __restrict__ cntf, int nb) {
  int i = blockIdx.x * 256 + threadIdx.x;
  if (i < 32768) {
    float s = 0.f;
    for (int b = 0; b < nb; b++) s += pesum[(size_t)b * 32768 + i];
    esum[i] = s;
  } else if (i < 33280) {
    int j = i - 32768;
    float s = 0.f;
    for (int b = 0; b < nb; b++) s += pcnt[b * 512 + j];
    cntf[j] = s;
  }
}

// EMA + ok-gate + dead-code reinit; single workgroup (needs global n and max)
__global__ __launch_bounds__(512) void k_finalize(const float* __restrict__ cbin,
                                                  const float* __restrict__ csin,
                                                  const float* __restrict__ eain,
                                                  const float* __restrict__ z,
                                                  const float* __restrict__ counts,
                                                  const float* __restrict__ esum,
                                                  const int* __restrict__ ridx,
                                                  const float* __restrict__ noise,
                                                  float* __restrict__ out) {
  __shared__ float red[512];
  int k = threadIdx.x;
  float cs = csin[k] * 0.99f + 0.01f * counts[k];
  red[k] = cs;
  __syncthreads();
  for (int off = 256; off > 0; off >>= 1) {
    if (k < off) red[k] += red[k + off];
    __syncthreads();
  }
  float nall = red[0];
  __syncthreads();
  float csn = ((cs + 1e-5f) / (nall + 0.00512f)) * nall;
  float eav[64], ncb[64];
  float lmax = 0.f;
  #pragma unroll
  for (int c = 0; c < 64; c++) {
    float e = eain[(k << 6) + c] * 0.99f + 0.01f * esum[(k << 6) + c];
    eav[c] = e;
    float v = e / csn;
    ncb[c] = v;
    float a = fabsf(v);
    if (isnan(v)) a = __builtin_inff();
    lmax = fmaxf(lmax, a);
  }
  red[k] = lmax;
  __syncthreads();
  for (int off = 256; off > 0; off >>= 1) {
    if (k < off) red[k] = fmaxf(red[k], red[k + off]);
    __syncthreads();
  }
  bool ok = red[0] < 10.0f;   // NaN -> inf -> false, matching reference gate
  bool dead = cs < 1.0f;
  int r = ridx[k];
  int rb = r >> 14, rs = r & 16383;
  #pragma unroll
  for (int c = 0; c < 64; c++) {
    float v = ok ? ncb[c] : cbin[(k << 6) + c];
    if (dead) v = z[((size_t)rb << 20) + ((size_t)c << 14) + rs] + noise[(k << 6) + c] * 0.01f;
    out[OFF_CB + (k << 6) + c] = v;
    out[OFF_EA + (k << 6) + c] = dead ? v : eav[c];
  }
  out[OFF_CS + k] = dead ? 1.0f : cs;
}

extern "C" void kernel_launch(void* const* d_in, const int* in_sizes, int n_in,
                              void* d_out, int out_size, void* d_ws, size_t ws_size,
                              hipStream_t stream) {
  const float* z  = (const float*)d_in[0];
  const float* cb = (const float*)d_in[1];
  const float* cs = (const float*)d_in[2];
  const float* ea = (const float*)d_in[3];
  float* out = (float*)d_out;
  char* ws = (char*)d_ws;
  int*   idxi   = (int*)(ws + WS_IDX);
  float* counts = (float*)(ws + WS_CNT);
  float* esum   = (float*)(ws + WS_ESUM);
  float* cnorm  = (float*)(ws + WS_CNORM);
  int*   ridx   = (int*)(ws + WS_RIDX);
  float* noise  = (float*)(ws + WS_NOISE);

  // pick largest power-of-2 partial count that fits ws (256 -> 1 block/CU)
  int nb = 0;
  for (int t = 256; t >= 1; t >>= 1)
    if ((size_t)WS_PART + (size_t)t * (131072 + 2048) <= ws_size) { nb = t; break; }

  k_rng<<<68, 256, 0, stream>>>(cb, noise, ridx, cnorm);
  k_argmin_zq<<<N_ / 64, 256, 0, stream>>>(z, cb, cnorm, idxi, out);
  if (nb >= 1) {
    float* pes = (float*)(ws + WS_PART);
    float* pcn = (float*)(ws + WS_PART + (size_t)nb * 131072);
    k_hist<<<nb, 256, 0, stream>>>(z, idxi, pes, pcn, N_ / nb, 0);
    k_hred<<<130, 256, 0, stream>>>(pes, pcn, esum, counts, nb);  // overwrites finals
  } else {
    // tiny-ws fallback: zero finals, flush histograms with global atomics
    hipMemsetAsync(ws + WS_CNT, 0, 2048 + 131072, stream);
    k_hist<<<8, 256, 0, stream>>>(z, idxi, esum, counts, N_ / 8, 1);
  }
  k_finalize<<<1, 512, 0, stream>>>(cb, cs, ea, z, counts, esum, ridx, noise, out);
}

// Round 10
// 740.199 us; speedup vs baseline: 1.0308x; 1.0308x over previous
//
#include <hip/hip_runtime.h>
#include <stdint.h>

// Problem constants: z (8,64,16,32,32) f32, codebook (512,64), N = 8*16*32*32
#define N_ 131072
#define K_ 512

// out offsets (in floats): z_q_st, z_q, indices, cb, cs, ea
#define OFF_ZQ   8388608
#define OFF_IDX  16777216
#define OFF_CB   16908288
#define OFF_CS   16941056
#define OFF_EA   16941568

// ws offsets (bytes)
#define WS_IDX   0         // int32 x 131072
#define WS_CNT   524288    // f32 x 512   (final counts)
#define WS_ESUM  526336    // f32 x 32768 (final embed_sum)
#define WS_CNORM 657408    // f32 x 512
#define WS_RIDX  659456    // int32 x 512
#define WS_NOISE 661504    // f32 x 32768
#define WS_PART  792576    // NB x (128KB esum partial) then NB x (2KB count partial)

// ---- JAX threefry2x32 (20 rounds), bit-exact ----
__device__ __forceinline__ void threefry(uint32_t k0, uint32_t k1,
                                         uint32_t x0, uint32_t x1,
                                         uint32_t& y0, uint32_t& y1) {
  uint32_t ks[3] = {k0, k1, k0 ^ k1 ^ 0x1BD11BDAu};
  const int R0[4] = {13, 15, 26, 6};
  const int R1[4] = {17, 29, 16, 24};
  x0 += ks[0]; x1 += ks[1];
  #pragma unroll
  for (int i = 0; i < 5; i++) {
    #pragma unroll
    for (int j = 0; j < 4; j++) {
      int r = (i & 1) ? R1[j] : R0[j];
      x0 += x1;
      x1 = (x1 << r) | (x1 >> (32 - r));
      x1 ^= x0;
    }
    x0 += ks[(i + 1) % 3];
    x1 += ks[(i + 2) % 3] + (uint32_t)(i + 1);
  }
  y0 = x0; y1 = x1;
}

// Giles erfinv (same polynomial XLA uses for f32)
__device__ __forceinline__ float erfinv_f(float x) {
  float w = -log1pf(-x * x);
  float p;
  if (w < 5.0f) {
    w -= 2.5f;
    p = 2.81022636e-08f;
    p = fmaf(p, w, 3.43273939e-07f);
    p = fmaf(p, w, -3.5233877e-06f);
    p = fmaf(p, w, -4.39150654e-06f);
    p = fmaf(p, w, 0.00021858087f);
    p = fmaf(p, w, -0.00125372503f);
    p = fmaf(p, w, -0.00417768164f);
    p = fmaf(p, w, 0.246640727f);
    p = fmaf(p, w, 1.50140941f);
  } else {
    w = sqrtf(w) - 3.0f;
    p = -0.000200214257f;
    p = fmaf(p, w, 0.000100950558f);
    p = fmaf(p, w, 0.00134934322f);
    p = fmaf(p, w, -0.00367342844f);
    p = fmaf(p, w, 0.00573950773f);
    p = fmaf(p, w, -0.0076224613f);
    p = fmaf(p, w, 0.00943887047f);
    p = fmaf(p, w, 1.00167406f);
    p = fmaf(p, w, 2.83297682f);
  }
  return p * x;
}

// RNG (ridx exact, noise approx-exact) + codebook row norms
__global__ __launch_bounds__(256) void k_rng(const float* __restrict__ cb,
                                             float* __restrict__ noise,
                                             int* __restrict__ ridx,
                                             float* __restrict__ cnorm) {
  int t = blockIdx.x * 256 + threadIdx.x;
  if (t < 16384) {
    // normal(key(2), (32768,)): pairs (i, i+16384)
    uint32_t y0, y1;
    threefry(0u, 2u, (uint32_t)t, (uint32_t)(t + 16384), y0, y1);
    const float lo = -0.99999994f;  // nextafter(-1, 0)
    float f0 = __uint_as_float(0x3F800000u | (y0 >> 9)) - 1.0f;
    float f1 = __uint_as_float(0x3F800000u | (y1 >> 9)) - 1.0f;
    float u0 = fmaxf(lo, f0 * 2.0f + lo);
    float u1 = fmaxf(lo, f1 * 2.0f + lo);
    noise[t]         = 1.41421356237309515f * erfinv_f(u0);
    noise[t + 16384] = 1.41421356237309515f * erfinv_f(u1);
  } else if (t < 16640) {
    // randint(key(1), (512,), 0, 131072): span=2^17 divides 2^32 so result
    // = lower_bits % 2^17, lower_bits from k2 of split(key(1)).
    int i = t - 16384;
    uint32_t a0, b0, a1, b1;
    threefry(0u, 1u, 0u, 2u, a0, b0);  // split lane 0
    threefry(0u, 1u, 1u, 3u, a1, b1);  // split lane 1 ; k2 = (b0, b1)
    uint32_t y0, y1;
    threefry(b0, b1, (uint32_t)i, (uint32_t)(i + 256), y0, y1);
    ridx[i]       = (int)(y0 & 0x1FFFFu);
    ridx[i + 256] = (int)(y1 & 0x1FFFFu);
  } else if (t < 17152) {
    int k = t - 16640;
    const float* ck = cb + (k << 6);
    float s = 0.f;
    #pragma unroll
    for (int c = 0; c < 64; c++) s = fmaf(ck[c], ck[c], s);
    cnorm[k] = s;
  }
}

// Fused distances + argmin + z_q/z_q_st stores. 4-wave K-split:
// block = 64 points; wave w scans codes [128w, 128w+128) with the SAME
// per-k serial fmaf chain as the validated full scan (bit-identical d),
// then an order-preserving LDS combine (ascending chunk, strict <) = global
// first-min argmin exactly. 2 codes/iter = 2 independent FMA chains for ILP.
// RULE #20 FIX vs round 9: the epilogue must NOT index zv[] with the
// runtime 'wave' value (that demoted zv to scratch: VGPR_Count 52,
// +131 MB WRITE_SIZE). zv is only ever indexed by compile-time constants;
// the epilogue re-loads zc from z (L1/L2-hot, just read by this block).
__global__ __launch_bounds__(256, 4) void k_argmin_zq(const float* __restrict__ z,
                                                      const float* __restrict__ cb,
                                                      const float* __restrict__ cnorm,
                                                      int* __restrict__ idxi,
                                                      float* __restrict__ out) {
  __shared__ float ld[256];
  __shared__ int   li[256];
  int tid = threadIdx.x;
  int wave = tid >> 6, lane = tid & 63;
  int n = blockIdx.x * 64 + lane;          // point index (lane-consecutive s)
  int b = n >> 14, s = n & 16383;
  const float* zp = z + ((size_t)b << 20) + s;
  float zv[64];
  #pragma unroll
  for (int c = 0; c < 64; c++) zv[c] = zp[(size_t)c << 14];  // coalesced per c
  float z2 = 0.f;
  #pragma unroll
  for (int c = 0; c < 64; c++) z2 = fmaf(zv[c], zv[c], z2);
  int k0 = wave << 7;
  float best = 3.4028235e38f; int bi = k0;
  #pragma unroll 1
  for (int k = k0; k < k0 + 128; k += 2) {
    const float* ca = cb + (k << 6);       // wave-uniform -> scalar loads
    const float* cbp = ca + 64;
    float da = 0.f, db = 0.f;
    #pragma unroll
    for (int c = 0; c < 64; c++) {
      da = fmaf(zv[c], ca[c], da);         // same chain order as validated scan
      db = fmaf(zv[c], cbp[c], db);
    }
    float d1 = (z2 + cnorm[k])     - 2.0f * da;
    float d2 = (z2 + cnorm[k + 1]) - 2.0f * db;
    if (d1 < best) { best = d1; bi = k; }      // first-min tie-break
    if (d2 < best) { best = d2; bi = k + 1; }
  }
  ld[tid] = best; li[tid] = bi;
  __syncthreads();
  float fb = ld[lane]; int fi = li[lane];
  #pragma unroll
  for (int w = 1; w < 4; w++) {
    float d = ld[(w << 6) + lane];
    int   i2 = li[(w << 6) + lane];
    if (d < fb) { fb = d; fi = i2; }       // strict < keeps lowest chunk on ties
  }
  if (wave == 0) {
    idxi[n] = fi;
    out[OFF_IDX + n] = (float)fi;
  }
  const float* cq = cb + (fi << 6);        // per-lane gather, cb L2-resident
  float* o1 = out + ((size_t)b << 20) + s; // z_q_st
  float* o2 = o1 + OFF_ZQ;                 // z_q
  #pragma unroll
  for (int cc = 0; cc < 16; cc++) {        // stores split: wave w owns 16 c's
    int c = (wave << 4) | cc;              // runtime c -> MEMORY index only
    float q = cq[c];
    float zc = zp[(size_t)c << 14];        // re-load, cache-hot (NOT zv[c]!)
    o1[(size_t)c << 14] = zc + (q - zc);   // fp-exact as reference computes it
    o2[(size_t)c << 14] = q;
  }
}

// LDS histogram of embed_sum[K][C] + counts[K]; zero global atomics on the
// main path (partials flushed with plain coalesced stores, reduced by k_hred).
// XOR bank swizzle (c ^ (k&31)): lanes-over-s accumulation would otherwise put
// all 64 lanes in bank c%32.
__global__ __launch_bounds__(256) void k_hist(const float* __restrict__ z,
                                              const int* __restrict__ idxi,
                                              float* __restrict__ pesum,
                                              float* __restrict__ pcnt,
                                              int ppb, int atomicFlush) {
  __shared__ float hist[32768];   // 128 KB
  __shared__ float cnt[512];
  int tid = threadIdx.x;
  for (int i = tid; i < 32768; i += 256) hist[i] = 0.f;
  if (tid < 256) { cnt[tid] = 0.f; cnt[tid + 256] = 0.f; }
  __syncthreads();
  int wave = tid >> 6, lane = tid & 63;
  int base = blockIdx.x * ppb;
  for (int g0 = wave * 64; g0 < ppb; g0 += 256) {
    int n = base + g0 + lane;
    int b = n >> 14, s = n & 16383;
    int k = idxi[n];
    const float* zp = z + ((size_t)b << 20) + s;
    atomicAdd(&cnt[k], 1.0f);
    int hb = k << 6, sw = k & 31;
    #pragma unroll 8
    for (int c = 0; c < 64; c++)
      atomicAdd(&hist[hb + (c ^ sw)], zp[(size_t)c << 14]);  // coalesced z read
  }
  __syncthreads();
  size_t pb = (size_t)blockIdx.x * 32768;
  for (int i = tid; i < 32768; i += 256) {
    int k = i >> 6, c = i & 63;
    float v = hist[(k << 6) + (c ^ (k & 31))];  // un-swizzle; LDS read conflict-free
    if (atomicFlush) { if (v != 0.f) atomicAdd(&pesum[i], v); }
    else pesum[pb + i] = v;
  }
  if (tid < 256) {
    #pragma unroll
    for (int j = 0; j < 2; j++) {
      int i = tid + j * 256;
      float v = cnt[i];
      if (atomicFlush) { if (v != 0.f) atomicAdd(&pcnt[i], v); }
      else pcnt[blockIdx.x * 512 + i] = v;
    }
  }
}

// Reduce NB partials -> final esum[32768] + counts[512]
__global__ __launch_bounds__(256) void k_hred(const float* __restrict__ pesum,
                                              const float* __restrict__ pcnt,
                                              float* __restrict__ esum,
                                              float* __restrict__ cntf, int nb) {
  int i = blockIdx.x * 256 + threadIdx.x;
  if (i < 32768) {
    float s = 0.f;
    for (int b = 0; b < nb; b++) s += pesum[(size_t)b * 32768 + i];
    esum[i] = s;
  } else if (i < 33280) {
    int j = i - 32768;
    float s = 0.f;
    for (int b = 0; b < nb; b++) s += pcnt[b * 512 + j];
    cntf[j] = s;
  }
}

// EMA + ok-gate + dead-code reinit; single workgroup (needs global n and max)
__global__ __launch_bounds__(512) void k_finalize(const float* __restrict__ cbin,
                                                  const float* __restrict__ csin,
                                                  const float* __restrict__ eain,
                                                  const float* __restrict__ z,
                                                  const float* __restrict__ counts,
                                                  const float* __restrict__ esum,
                                                  const int* __restrict__ ridx,
                                                  const float* __restrict__ noise,
                                                  float* __restrict__ out) {
  __shared__ float red[512];
  int k = threadIdx.x;
  float cs = csin[k] * 0.99f + 0.01f * counts[k];
  red[k] = cs;
  __syncthreads();
  for (int off = 256; off > 0; off >>= 1) {
    if (k < off) red[k] += red[k + off];
    __syncthreads();
  }
  float nall = red[0];
  __syncthreads();
  float csn = ((cs + 1e-5f) / (nall + 0.00512f)) * nall;
  float eav[64], ncb[64];
  float lmax = 0.f;
  #pragma unroll
  for (int c = 0; c < 64; c++) {
    float e = eain[(k << 6) + c] * 0.99f + 0.01f * esum[(k << 6) + c];
    eav[c] = e;
    float v = e / csn;
    ncb[c] = v;
    float a = fabsf(v);
    if (isnan(v)) a = __builtin_inff();
    lmax = fmaxf(lmax, a);
  }
  red[k] = lmax;
  __syncthreads();
  for (int off = 256; off > 0; off >>= 1) {
    if (k < off) red[k] = fmaxf(red[k], red[k + off]);
    __syncthreads();
  }
  bool ok = red[0] < 10.0f;   // NaN -> inf -> false, matching reference gate
  bool dead = cs < 1.0f;
  int r = ridx[k];
  int rb = r >> 14, rs = r & 16383;
  #pragma unroll
  for (int c = 0; c < 64; c++) {
    float v = ok ? ncb[c] : cbin[(k << 6) + c];
    if (dead) v = z[((size_t)rb << 20) + ((size_t)c << 14) + rs] + noise[(k << 6) + c] * 0.01f;
    out[OFF_CB + (k << 6) + c] = v;
    out[OFF_EA + (k << 6) + c] = dead ? v : eav[c];
  }
  out[OFF_CS + k] = dead ? 1.0f : cs;
}

extern "C" void kernel_launch(void* const* d_in, const int* in_sizes, int n_in,
                              void* d_out, int out_size, void* d_ws, size_t ws_size,
                              hipStream_t stream) {
  const float* z  = (const float*)d_in[0];
  const float* cb = (const float*)d_in[1];
  const float* cs = (const float*)d_in[2];
  const float* ea = (const float*)d_in[3];
  float* out = (float*)d_out;
  char* ws = (char*)d_ws;
  int*   idxi   = (int*)(ws + WS_IDX);
  float* counts = (float*)(ws + WS_CNT);
  float* esum   = (float*)(ws + WS_ESUM);
  float* cnorm  = (float*)(ws + WS_CNORM);
  int*   ridx   = (int*)(ws + WS_RIDX);
  float* noise  = (float*)(ws + WS_NOISE);

  // pick largest power-of-2 partial count that fits ws (256 -> 1 block/CU)
  int nb = 0;
  for (int t = 256; t >= 1; t >>= 1)
    if ((size_t)WS_PART + (size_t)t * (131072 + 2048) <= ws_size) { nb = t; break; }

  k_rng<<<68, 256, 0, stream>>>(cb, noise, ridx, cnorm);
  k_argmin_zq<<<N_ / 64, 256, 0, stream>>>(z, cb, cnorm, idxi, out);
  if (nb >= 1) {
    float* pes = (float*)(ws + WS_PART);
    float* pcn = (float*)(ws + WS_PART + (size_t)nb * 131072);
    k_hist<<<nb, 256, 0, stream>>>(z, idxi, pes, pcn, N_ / nb, 0);
    k_hred<<<130, 256, 0, stream>>>(pes, pcn, esum, counts, nb);  // overwrites finals
  } else {
    // tiny-ws fallback: zero finals, flush histograms with global atomics
    hipMemsetAsync(ws + WS_CNT, 0, 2048 + 131072, stream);
    k_hist<<<8, 256, 0, stream>>>(z, idxi, esum, counts, N_ / 8, 1);
  }
  k_finalize<<<1, 512, 0, stream>>>(cb, cs, ea, z, counts, esum, ridx, noise, out);
}

// Round 11
// 420.816 us; speedup vs baseline: 1.8131x; 1.7590x over previous
//
#include <hip/hip_runtime.h>
#include <stdint.h>

// Problem constants: z (8,64,16,32,32) f32, codebook (512,64), N = 8*16*32*32
#define N_ 131072
#define K_ 512

// out offsets (in floats): z_q_st, z_q, indices, cb, cs, ea
#define OFF_ZQ   8388608
#define OFF_IDX  16777216
#define OFF_CB   16908288
#define OFF_CS   16941056
#define OFF_EA   16941568

// ws offsets (bytes)
#define WS_IDX   0         // int32 x 131072
#define WS_CNT   524288    // f32 x 512   (final counts)
#define WS_ESUM  526336    // f32 x 32768 (final embed_sum)
#define WS_CNORM 657408    // f32 x 512
#define WS_RIDX  659456    // int32 x 512
#define WS_NOISE 661504    // f32 x 32768
#define WS_PART  792576    // NB x (128KB esum partial) then NB x (2KB count partial)

// ---- JAX threefry2x32 (20 rounds), bit-exact ----
__device__ __forceinline__ void threefry(uint32_t k0, uint32_t k1,
                                         uint32_t x0, uint32_t x1,
                                         uint32_t& y0, uint32_t& y1) {
  uint32_t ks[3] = {k0, k1, k0 ^ k1 ^ 0x1BD11BDAu};
  const int R0[4] = {13, 15, 26, 6};
  const int R1[4] = {17, 29, 16, 24};
  x0 += ks[0]; x1 += ks[1];
  #pragma unroll
  for (int i = 0; i < 5; i++) {
    #pragma unroll
    for (int j = 0; j < 4; j++) {
      int r = (i & 1) ? R1[j] : R0[j];
      x0 += x1;
      x1 = (x1 << r) | (x1 >> (32 - r));
      x1 ^= x0;
    }
    x0 += ks[(i + 1) % 3];
    x1 += ks[(i + 2) % 3] + (uint32_t)(i + 1);
  }
  y0 = x0; y1 = x1;
}

// Giles erfinv (same polynomial XLA uses for f32)
__device__ __forceinline__ float erfinv_f(float x) {
  float w = -log1pf(-x * x);
  float p;
  if (w < 5.0f) {
    w -= 2.5f;
    p = 2.81022636e-08f;
    p = fmaf(p, w, 3.43273939e-07f);
    p = fmaf(p, w, -3.5233877e-06f);
    p = fmaf(p, w, -4.39150654e-06f);
    p = fmaf(p, w, 0.00021858087f);
    p = fmaf(p, w, -0.00125372503f);
    p = fmaf(p, w, -0.00417768164f);
    p = fmaf(p, w, 0.246640727f);
    p = fmaf(p, w, 1.50140941f);
  } else {
    w = sqrtf(w) - 3.0f;
    p = -0.000200214257f;
    p = fmaf(p, w, 0.000100950558f);
    p = fmaf(p, w, 0.00134934322f);
    p = fmaf(p, w, -0.00367342844f);
    p = fmaf(p, w, 0.00573950773f);
    p = fmaf(p, w, -0.0076224613f);
    p = fmaf(p, w, 0.00943887047f);
    p = fmaf(p, w, 1.00167406f);
    p = fmaf(p, w, 2.83297682f);
  }
  return p * x;
}

// RNG (ridx exact, noise approx-exact) + codebook row norms
__global__ __launch_bounds__(256) void k_rng(const float* __restrict__ cb,
                                             float* __restrict__ noise,
                                             int* __restrict__ ridx,
                                             float* __restrict__ cnorm) {
  int t = blockIdx.x * 256 + threadIdx.x;
  if (t < 16384) {
    // normal(key(2), (32768,)): pairs (i, i+16384)
    uint32_t y0, y1;
    threefry(0u, 2u, (uint32_t)t, (uint32_t)(t + 16384), y0, y1);
    const float lo = -0.99999994f;  // nextafter(-1, 0)
    float f0 = __uint_as_float(0x3F800000u | (y0 >> 9)) - 1.0f;
    float f1 = __uint_as_float(0x3F800000u | (y1 >> 9)) - 1.0f;
    float u0 = fmaxf(lo, f0 * 2.0f + lo);
    float u1 = fmaxf(lo, f1 * 2.0f + lo);
    noise[t]         = 1.41421356237309515f * erfinv_f(u0);
    noise[t + 16384] = 1.41421356237309515f * erfinv_f(u1);
  } else if (t < 16640) {
    // randint(key(1), (512,), 0, 131072): span=2^17 divides 2^32 so result
    // = lower_bits % 2^17, lower_bits from k2 of split(key(1)).
    int i = t - 16384;
    uint32_t a0, b0, a1, b1;
    threefry(0u, 1u, 0u, 2u, a0, b0);  // split lane 0
    threefry(0u, 1u, 1u, 3u, a1, b1);  // split lane 1 ; k2 = (b0, b1)
    uint32_t y0, y1;
    threefry(b0, b1, (uint32_t)i, (uint32_t)(i + 256), y0, y1);
    ridx[i]       = (int)(y0 & 0x1FFFFu);
    ridx[i + 256] = (int)(y1 & 0x1FFFFu);
  } else if (t < 17152) {
    int k = t - 16640;
    const float* ck = cb + (k << 6);
    float s = 0.f;
    #pragma unroll
    for (int c = 0; c < 64; c++) s = fmaf(ck[c], ck[c], s);
    cnorm[k] = s;
  }
}

// Fused distances + argmin + z_q/z_q_st stores. 4-wave K-split, LDS-staged z.
// Round-10 post-mortem fixes:
//  (a) z lives in LDS [c][point] (VGPR=52 proved hipcc never register-cached
//      zv[64]; it re-loaded global per k). LDS reads: lane -> zs[c*64+lane],
//      consecutive = 2 lanes/bank = conflict-free. Same f32 bits -> distances
//      bit-identical.
//  (b) wave id via readfirstlane -> k/cnorm/codebook-row pointers provably
//      wave-uniform -> s_load scalar path (round 7-10 lost this: tid-derived
//      k0 forced per-lane vector loads of cb).
//  (c) 4 codes/iter: 1 ds_read feeds 4 FMAs, 4 independent chains for ILP.
// Exactness: per-code serial c-order fmaf chain unchanged; e0..e3 compared
// ascending with strict < ; ascending-wave LDS combine = global first-min.
__global__ __launch_bounds__(256, 4) void k_argmin_zq(const float* __restrict__ z,
                                                      const float* __restrict__ cb,
                                                      const float* __restrict__ cnorm,
                                                      int* __restrict__ idxi,
                                                      float* __restrict__ out) {
  __shared__ float zs[4096];    // [c][point] 16 KB
  __shared__ float ld[256];
  __shared__ int   li[256];
  int tid = threadIdx.x;
  int lane = tid & 63;
  int wv = __builtin_amdgcn_readfirstlane(tid >> 6);  // wave id as SGPR
  int n0 = blockIdx.x * 64;              // block's 64 consecutive points
  int b = n0 >> 14, s0 = n0 & 16383;     // same b for whole block (64 | 16384)
  const float* zb = z + ((size_t)b << 20) + s0;
  // stage: wave wv loads channels [wv*16, wv*16+16); coalesced global,
  // conflict-free LDS write
  #pragma unroll
  for (int cc = 0; cc < 16; cc++) {
    int c = (wv << 4) | cc;
    zs[(c << 6) | lane] = zb[((size_t)c << 14) + lane];
  }
  __syncthreads();
  // z2, serial c-order chain (bit-identical to validated scan)
  float z2 = 0.f;
  #pragma unroll
  for (int c = 0; c < 64; c++) {
    float zc = zs[(c << 6) | lane];
    z2 = fmaf(zc, zc, z2);
  }
  int k0 = wv << 7;
  float best = 3.4028235e38f; int bi = k0;
  #pragma unroll 1
  for (int k = k0; k < k0 + 128; k += 4) {
    const float* c0 = cb + (k << 6);     // SGPR pointer -> s_load rows
    const float* c1 = c0 + 64;
    const float* c2 = c0 + 128;
    const float* c3 = c0 + 192;
    float d0 = 0.f, d1 = 0.f, d2 = 0.f, d3 = 0.f;
    #pragma unroll
    for (int c = 0; c < 64; c++) {
      float zc = zs[(c << 6) | lane];
      d0 = fmaf(zc, c0[c], d0);          // same chain order as validated scan
      d1 = fmaf(zc, c1[c], d1);
      d2 = fmaf(zc, c2[c], d2);
      d3 = fmaf(zc, c3[c], d3);
    }
    float e0 = (z2 + cnorm[k])     - 2.0f * d0;
    float e1 = (z2 + cnorm[k + 1]) - 2.0f * d1;
    float e2 = (z2 + cnorm[k + 2]) - 2.0f * d2;
    float e3 = (z2 + cnorm[k + 3]) - 2.0f * d3;
    if (e0 < best) { best = e0; bi = k; }      // first-min tie-break
    if (e1 < best) { best = e1; bi = k + 1; }
    if (e2 < best) { best = e2; bi = k + 2; }
    if (e3 < best) { best = e3; bi = k + 3; }
  }
  ld[tid] = best; li[tid] = bi;
  __syncthreads();
  float fb = ld[lane]; int fi = li[lane];
  #pragma unroll
  for (int w = 1; w < 4; w++) {
    float d = ld[(w << 6) + lane];
    int   i2 = li[(w << 6) + lane];
    if (d < fb) { fb = d; fi = i2; }     // strict < keeps lowest chunk on ties
  }
  if (wv == 0) {
    idxi[n0 + lane] = fi;
    out[OFF_IDX + n0 + lane] = (float)fi;
  }
  const float* cq = cb + (fi << 6);      // per-lane gather, cb L2-resident
  float* o1 = out + ((size_t)b << 20) + s0 + lane;  // z_q_st
  float* o2 = o1 + OFF_ZQ;                          // z_q
  #pragma unroll
  for (int cc = 0; cc < 16; cc++) {      // stores split: wave wv owns 16 c's
    int c = (wv << 4) | cc;              // runtime c -> memory index only
    float q = cq[c];
    float zc = zs[(c << 6) | lane];      // LDS, not a register array
    o1[(size_t)c << 14] = zc + (q - zc); // fp-exact as reference computes it
    o2[(size_t)c << 14] = q;
  }
}

// LDS histogram of embed_sum[K][C] + counts[K]; zero global atomics on the
// main path (partials flushed with plain coalesced stores, reduced by k_hred).
// XOR bank swizzle (c ^ (k&31)): lanes-over-s accumulation would otherwise put
// all 64 lanes in bank c%32.
__global__ __launch_bounds__(256) void k_hist(const float* __restrict__ z,
                                              const int* __restrict__ idxi,
                                              float* __restrict__ pesum,
                                              float* __restrict__ pcnt,
                                              int ppb, int atomicFlush) {
  __shared__ float hist[32768];   // 128 KB
  __shared__ float cnt[512];
  int tid = threadIdx.x;
  for (int i = tid; i < 32768; i += 256) hist[i] = 0.f;
  if (tid < 256) { cnt[tid] = 0.f; cnt[tid + 256] = 0.f; }
  __syncthreads();
  int wave = tid >> 6, lane = tid & 63;
  int base = blockIdx.x * ppb;
  for (int g0 = wave * 64; g0 < ppb; g0 += 256) {
    int n = base + g0 + lane;
    int b = n >> 14, s = n & 16383;
    int k = idxi[n];
    const float* zp = z + ((size_t)b << 20) + s;
    atomicAdd(&cnt[k], 1.0f);
    int hb = k << 6, sw = k & 31;
    #pragma unroll 8
    for (int c = 0; c < 64; c++)
      atomicAdd(&hist[hb + (c ^ sw)], zp[(size_t)c << 14]);  // coalesced z read
  }
  __syncthreads();
  size_t pb = (size_t)blockIdx.x * 32768;
  for (int i = tid; i < 32768; i += 256) {
    int k = i >> 6, c = i & 63;
    float v = hist[(k << 6) + (c ^ (k & 31))];  // un-swizzle; LDS read conflict-free
    if (atomicFlush) { if (v != 0.f) atomicAdd(&pesum[i], v); }
    else pesum[pb + i] = v;
  }
  if (tid < 256) {
    #pragma unroll
    for (int j = 0; j < 2; j++) {
      int i = tid + j * 256;
      float v = cnt[i];
      if (atomicFlush) { if (v != 0.f) atomicAdd(&pcnt[i], v); }
      else pcnt[blockIdx.x * 512 + i] = v;
    }
  }
}

// Reduce NB partials -> final esum[32768] + counts[512]
__global__ __launch_bounds__(256) void k_hred(const float* __restrict__ pesum,
                                              const float* __restrict__ pcnt,
                                              float* __restrict__ esum,
                                              float* __restrict__ cntf, int nb) {
  int i = blockIdx.x * 256 + threadIdx.x;
  if (i < 32768) {
    float s = 0.f;
    for (int b = 0; b < nb; b++) s += pesum[(size_t)b * 32768 + i];
    esum[i] = s;
  } else if (i < 33280) {
    int j = i - 32768;
    float s = 0.f;
    for (int b = 0; b < nb; b++) s += pcnt[b * 512 + j];
    cntf[j] = s;
  }
}

// EMA + ok-gate + dead-code reinit; single workgroup (needs global n and max)
__global__ __launch_bounds__(512) void k_finalize(const float* __restrict__ cbin,
                                                  const float* __restrict__ csin,
                                                  const float* __restrict__ eain,
                                                  const float* __restrict__ z,
                                                  const float* __restrict__ counts,
                                                  const float* __restrict__ esum,
                                                  const int* __restrict__ ridx,
                                                  const float* __restrict__ noise,
                                                  float* __restrict__ out) {
  __shared__ float red[512];
  int k = threadIdx.x;
  float cs = csin[k] * 0.99f + 0.01f * counts[k];
  red[k] = cs;
  __syncthreads();
  for (int off = 256; off > 0; off >>= 1) {
    if (k < off) red[k] += red[k + off];
    __syncthreads();
  }
  float nall = red[0];
  __syncthreads();
  float csn = ((cs + 1e-5f) / (nall + 0.00512f)) * nall;
  float eav[64], ncb[64];
  float lmax = 0.f;
  #pragma unroll
  for (int c = 0; c < 64; c++) {
    float e = eain[(k << 6) + c] * 0.99f + 0.01f * esum[(k << 6) + c];
    eav[c] = e;
    float v = e / csn;
    ncb[c] = v;
    float a = fabsf(v);
    if (isnan(v)) a = __builtin_inff();
    lmax = fmaxf(lmax, a);
  }
  red[k] = lmax;
  __syncthreads();
  for (int off = 256; off > 0; off >>= 1) {
    if (k < off) red[k] = fmaxf(red[k], red[k + off]);
    __syncthreads();
  }
  bool ok = red[0] < 10.0f;   // NaN -> inf -> false, matching reference gate
  bool dead = cs < 1.0f;
  int r = ridx[k];
  int rb = r >> 14, rs = r & 16383;
  #pragma unroll
  for (int c = 0; c < 64; c++) {
    float v = ok ? ncb[c] : cbin[(k << 6) + c];
    if (dead) v = z[((size_t)rb << 20) + ((size_t)c << 14) + rs] + noise[(k << 6) + c] * 0.01f;
    out[OFF_CB + (k << 6) + c] = v;
    out[OFF_EA + (k << 6) + c] = dead ? v : eav[c];
  }
  out[OFF_CS + k] = dead ? 1.0f : cs;
}

extern "C" void kernel_launch(void* const* d_in, const int* in_sizes, int n_in,
                              void* d_out, int out_size, void* d_ws, size_t ws_size,
                              hipStream_t stream) {
  const float* z  = (const float*)d_in[0];
  const float* cb = (const float*)d_in[1];
  const float* cs = (const float*)d_in[2];
  const float* ea = (const float*)d_in[3];
  float* out = (float*)d_out;
  char* ws = (char*)d_ws;
  int*   idxi   = (int*)(ws + WS_IDX);
  float* counts = (float*)(ws + WS_CNT);
  float* esum   = (float*)(ws + WS_ESUM);
  float* cnorm  = (float*)(ws + WS_CNORM);
  int*   ridx   = (int*)(ws + WS_RIDX);
  float* noise  = (float*)(ws + WS_NOISE);

  // pick largest power-of-2 partial count that fits ws (256 -> 1 block/CU)
  int nb = 0;
  for (int t = 256; t >= 1; t >>= 1)
    if ((size_t)WS_PART + (size_t)t * (131072 + 2048) <= ws_size) { nb = t; break; }

  k_rng<<<68, 256, 0, stream>>>(cb, noise, ridx, cnorm);
  k_argmin_zq<<<N_ / 64, 256, 0, stream>>>(z, cb, cnorm, idxi, out);
  if (nb >= 1) {
    float* pes = (float*)(ws + WS_PART);
    float* pcn = (float*)(ws + WS_PART + (size_t)nb * 131072);
    k_hist<<<nb, 256, 0, stream>>>(z, idxi, pes, pcn, N_ / nb, 0);
    k_hred<<<130, 256, 0, stream>>>(pes, pcn, esum, counts, nb);  // overwrites finals
  } else {
    // tiny-ws fallback: zero finals, flush histograms with global atomics
    hipMemsetAsync(ws + WS_CNT, 0, 2048 + 131072, stream);
    k_hist<<<8, 256, 0, stream>>>(z, idxi, esum, counts, N_ / 8, 1);
  }
  k_finalize<<<1, 512, 0, stream>>>(cb, cs, ea, z, counts, esum, ridx, noise, out);
}